// Round 1
// baseline (2802.889 us; speedup 1.0000x reference)
//
#include <hip/hip_runtime.h>
#include <hip/hip_bf16.h>

#define DI __device__ __forceinline__

typedef unsigned int u32;
typedef unsigned short u16;

DI float bf2f_lo(u32 u) { union { u32 x; float f; } t; t.x = u << 16; return t.f; }
DI float bf2f_hi(u32 u) { union { u32 x; float f; } t; t.x = u & 0xffff0000u; return t.f; }
DI u16 f2bf(float f) {
  union { float f; u32 x; } t; t.f = f;
  u32 x = t.x;
  u32 r = (x + 0x7fffu + ((x >> 16) & 1u)) >> 16;   // RNE
  return (u16)r;
}

// ---------------- conv1: x[256,1,28,28] -> h[256,256,20,20] ----------------
// grid (256 b, 2 oc-halves), 256 thr. LDS: x image + 128 w rows.
__global__ __launch_bounds__(256) void conv1_kernel(
    const float* __restrict__ x, const float* __restrict__ w1,
    const float* __restrict__ b1, float* __restrict__ h) {
  __shared__ float xs[784];
  __shared__ float ws[10368]; // 128 oc * 81
  int b = blockIdx.x, oh = blockIdx.y, tid = threadIdx.x;
  const float* xb = x + (size_t)b * 784;
  for (int i = tid; i < 784; i += 256) xs[i] = xb[i];
  for (int i = tid; i < 10368; i += 256) ws[i] = w1[(size_t)oh * 10368 + i];
  __syncthreads();
  int ocl = tid & 127, yh = tid >> 7;
  int oc = oh * 128 + ocl;
  const float* w = ws + ocl * 81;
  float bias = b1[oc];
  float* hb = h + (size_t)b * 102400 + (size_t)oc * 400;
  for (int y = yh * 10; y < yh * 10 + 10; ++y) {
    float acc[20];
#pragma unroll
    for (int i = 0; i < 20; ++i) acc[i] = bias;
    for (int ky = 0; ky < 9; ++ky) {
      float wr[9];
#pragma unroll
      for (int i = 0; i < 9; ++i) wr[i] = w[ky * 9 + i];
      float xr[28];
#pragma unroll
      for (int i = 0; i < 28; ++i) xr[i] = xs[(y + ky) * 28 + i];
#pragma unroll
      for (int xx = 0; xx < 20; ++xx) {
#pragma unroll
        for (int kx = 0; kx < 9; ++kx) acc[xx] += xr[xx + kx] * wr[kx];
      }
    }
#pragma unroll
    for (int xx = 0; xx < 20; ++xx) hb[y * 20 + xx] = acc[xx];
  }
}

// ---------------- w2 transpose: w2[oc][m=ic*81+k] -> w2t[m][oc] ----------------
__global__ __launch_bounds__(256) void w2t_kernel(
    const float* __restrict__ w2, float* __restrict__ w2t) {
  __shared__ float tile[32][33];
  int m0 = blockIdx.x * 32, oc0 = blockIdx.y * 32;
  int tx = threadIdx.x & 31, ty = threadIdx.x >> 5; // 32x8
  for (int r = ty; r < 32; r += 8) tile[r][tx] = w2[(size_t)(oc0 + r) * 20736 + m0 + tx];
  __syncthreads();
  for (int r = ty; r < 32; r += 8) w2t[(size_t)(m0 + r) * 256 + oc0 + tx] = tile[tx][r];
}

// ---------------- conv2: h[256,256,20,20] -> prim[256,256,6,6] (9x9 s2) ----------------
// grid (256 b, 2 oc-halves), 256 thr; thread = 2 oc x 9 px (3x3 tile). h chunk in LDS.
__global__ __launch_bounds__(256) void conv2_kernel(
    const float* __restrict__ h, const float* __restrict__ w2t,
    const float* __restrict__ b2, float* __restrict__ prim) {
  __shared__ float hs[3200]; // 8 ic * 400
  int b = blockIdx.x, oh = blockIdx.y, tid = threadIdx.x;
  int og = tid & 63, pg = tid >> 6;
  int py0 = (pg >> 1) * 3, px0 = (pg & 1) * 3;
  int oc0 = oh * 128 + og * 2;
  float acc[2][9];
#pragma unroll
  for (int q = 0; q < 2; ++q) {
    float bv = b2[oc0 + q];
#pragma unroll
    for (int p = 0; p < 9; ++p) acc[q][p] = bv;
  }
  const float* hb = h + (size_t)b * 102400;
  for (int ic0 = 0; ic0 < 256; ic0 += 8) {
    __syncthreads();
    for (int i = tid; i < 3200; i += 256) hs[i] = hb[ic0 * 400 + i];
    __syncthreads();
    for (int ici = 0; ici < 8; ++ici) {
      const float* hsi = hs + ici * 400;
      const float* wb = w2t + (size_t)(ic0 + ici) * 81 * 256 + oc0;
      for (int ky = 0; ky < 9; ++ky) {
#pragma unroll
        for (int kx = 0; kx < 9; ++kx) {
          const float2 wv = *(const float2*)(wb + (ky * 9 + kx) * 256);
          float hv[9];
#pragma unroll
          for (int dy = 0; dy < 3; ++dy)
#pragma unroll
            for (int dx = 0; dx < 3; ++dx)
              hv[dy * 3 + dx] = hsi[(2 * py0 + 2 * dy + ky) * 20 + 2 * px0 + 2 * dx + kx];
#pragma unroll
          for (int p = 0; p < 9; ++p) {
            acc[0][p] += wv.x * hv[p];
            acc[1][p] += wv.y * hv[p];
          }
        }
      }
    }
  }
  float* pb = prim + (size_t)b * 9216;
#pragma unroll
  for (int q = 0; q < 2; ++q) {
#pragma unroll
    for (int p = 0; p < 9; ++p) {
      int y = py0 + p / 3, xx = px0 + p % 3;
      pb[(oc0 + q) * 36 + y * 6 + xx] = acc[q][p];
    }
  }
}

// ---------------- u_hat: prim -> U[b][m=loc*10+i][o] (bf16) ----------------
// prim_r[b,j,k,l,c] = prim_flat[b][j*288+k*48+l*8+c] (raw torch .view semantics)
__global__ __launch_bounds__(256) void uhat_kernel(
    const float* __restrict__ prim, const float* __restrict__ W,
    const float* __restrict__ Wb, u16* __restrict__ U) {
  __shared__ float Ws[1280];  // [i][o][c] for this loc
  __shared__ float Wbs[160];  // [i][o]
  __shared__ float ps[2048];  // [b][c]
  int loc = blockIdx.x, tid = threadIdx.x;
  int j = loc / 36, k = (loc / 6) % 6, l = loc % 6;
  size_t wbase = (size_t)j * 4608 + k * 768 + l * 128;
  for (int t = tid; t < 1280; t += 256) {
    int i = t >> 7, rem = t & 127;
    Ws[t] = W[(size_t)i * 147456 + wbase + rem];
  }
  for (int t = tid; t < 160; t += 256) {
    int i = t / 16, o = t & 15;
    Wbs[t] = Wb[(size_t)i * 18432 + j * 576 + k * 96 + l * 16 + o];
  }
  int pbase = j * 288 + k * 48 + l * 8;
  for (int t = tid; t < 2048; t += 256) {
    int bb = t >> 3, c = t & 7;
    ps[t] = prim[(size_t)bb * 9216 + pbase + c];
  }
  __syncthreads();
  int b = tid;
  float pr[8];
#pragma unroll
  for (int c = 0; c < 8; ++c) pr[c] = ps[b * 8 + c];
  u16* Ub = U + ((size_t)b * 11520 + (size_t)loc * 10) * 16;
  for (int i = 0; i < 10; ++i) {
#pragma unroll
    for (int o = 0; o < 16; ++o) {
      float a = Wbs[i * 16 + o];
#pragma unroll
      for (int c = 0; c < 8; ++c) a += pr[c] * Ws[i * 128 + o * 8 + c];
      Ub[i * 16 + o] = f2bf(a);
    }
  }
}

// ---------------- routing ----------------
__global__ __launch_bounds__(256) void softmax_kernel(
    const float* __restrict__ bij, float* __restrict__ c) {
  __shared__ float red[256];
  int i = blockIdx.x, tid = threadIdx.x;
  float m = -1e30f;
  for (int n = tid; n < 1152; n += 256) m = fmaxf(m, bij[i * 1152 + n]);
  red[tid] = m; __syncthreads();
  for (int s = 128; s > 0; s >>= 1) { if (tid < s) red[tid] = fmaxf(red[tid], red[tid + s]); __syncthreads(); }
  m = red[0]; __syncthreads();
  float sum = 0.f;
  for (int n = tid; n < 1152; n += 256) sum += expf(bij[i * 1152 + n] - m);
  red[tid] = sum; __syncthreads();
  for (int s = 128; s > 0; s >>= 1) { if (tid < s) red[tid] += red[tid + s]; __syncthreads(); }
  float inv = 1.0f / red[0];
  for (int n = tid; n < 1152; n += 256) c[i * 1152 + n] = expf(bij[i * 1152 + n] - m) * inv;
}

// v[b,i,k] = sum_n c[i,n] * U[b][i*1152+n][k]
__global__ __launch_bounds__(256) void vpass_kernel(
    const u16* __restrict__ U, const float* __restrict__ c, float* __restrict__ v) {
  __shared__ float red[256][17];
  int b = blockIdx.x, i = blockIdx.y, tid = threadIdx.x;
  float acc[16];
#pragma unroll
  for (int k = 0; k < 16; ++k) acc[k] = 0.f;
  const u16* Ub = U + ((size_t)b * 11520 + (size_t)i * 1152) * 16;
  for (int n = tid; n < 1152; n += 256) {
    float cv = c[i * 1152 + n];
    const uint4* row = (const uint4*)(Ub + (size_t)n * 16);
    uint4 r0 = row[0], r1 = row[1];
    u32 rr[8] = {r0.x, r0.y, r0.z, r0.w, r1.x, r1.y, r1.z, r1.w};
#pragma unroll
    for (int q = 0; q < 8; ++q) {
      acc[2 * q]     += cv * bf2f_lo(rr[q]);
      acc[2 * q + 1] += cv * bf2f_hi(rr[q]);
    }
  }
#pragma unroll
  for (int k = 0; k < 16; ++k) red[tid][k] = acc[k];
  __syncthreads();
  for (int s = 128; s > 0; s >>= 1) {
    if (tid < s) {
#pragma unroll
      for (int k = 0; k < 16; ++k) red[tid][k] += red[tid + s][k];
    }
    __syncthreads();
  }
  if (tid < 16) v[(size_t)b * 160 + i * 16 + tid] = red[0][tid];
}

// squash over whole batch per class; optionally emit final output [i][b][k]
__global__ __launch_bounds__(256) void squash_kernel(
    float* __restrict__ v, float* __restrict__ out, int finalf) {
  __shared__ float red[256];
  int i = blockIdx.x, tid = threadIdx.x;
  float s = 0.f;
  for (int t = tid; t < 4096; t += 256) {
    int bb = t >> 4, k = t & 15;
    float xv = v[bb * 160 + i * 16 + k];
    s += xv * xv;
  }
  red[tid] = s; __syncthreads();
  for (int st = 128; st > 0; st >>= 1) { if (tid < st) red[tid] += red[tid + st]; __syncthreads(); }
  float nrm = sqrtf(red[0]);
  float n2 = nrm * nrm;
  float scale = (n2 / (1.f + n2)) / nrm;
  for (int t = tid; t < 4096; t += 256) {
    int bb = t >> 4, k = t & 15;
    float xv = v[bb * 160 + i * 16 + k] * scale;
    if (finalf) out[(size_t)i * 4096 + bb * 16 + k] = xv;
    else v[bb * 160 + i * 16 + k] = xv;
  }
}

// partial bij update: part[bz][i][n] = sum_{b in chunk,k} U[b][i*1152+n][k]*v[b,i,k]
__global__ __launch_bounds__(256) void bij_partial_kernel(
    const u16* __restrict__ U, const float* __restrict__ v, float* __restrict__ part) {
  int nc = blockIdx.x, i = blockIdx.y, bz = blockIdx.z, tid = threadIdx.x;
  int n = nc * 256 + tid;
  if (n >= 1152) return;
  float s = 0.f;
  for (int bb = bz * 32; bb < bz * 32 + 32; ++bb) {
    const uint4* row = (const uint4*)(U + ((size_t)bb * 11520 + (size_t)i * 1152 + n) * 16);
    uint4 r0 = row[0], r1 = row[1];
    const float* vb = v + (size_t)bb * 160 + i * 16;
    u32 rr[8] = {r0.x, r0.y, r0.z, r0.w, r1.x, r1.y, r1.z, r1.w};
#pragma unroll
    for (int q = 0; q < 8; ++q) {
      s += bf2f_lo(rr[q]) * vb[2 * q];
      s += bf2f_hi(rr[q]) * vb[2 * q + 1];
    }
  }
  part[((size_t)bz * 10 + i) * 1152 + n] = s;
}

__global__ __launch_bounds__(256) void bij_reduce_kernel(
    const float* __restrict__ part, float* __restrict__ bij) {
  int idx = blockIdx.x * 256 + threadIdx.x;
  if (idx >= 11520) return;
  float s = bij[idx];
#pragma unroll
  for (int bz = 0; bz < 8; ++bz) s += part[(size_t)bz * 11520 + idx];
  bij[idx] = s;
}

extern "C" void kernel_launch(void* const* d_in, const int* in_sizes, int n_in,
                              void* d_out, int out_size, void* d_ws, size_t ws_size,
                              hipStream_t stream) {
  const float* x  = (const float*)d_in[0];
  const float* w1 = (const float*)d_in[1];
  const float* b1 = (const float*)d_in[2];
  const float* w2 = (const float*)d_in[3];
  const float* b2 = (const float*)d_in[4];
  const float* W  = (const float*)d_in[5];
  const float* Wb = (const float*)d_in[6];
  float* out = (float*)d_out;

  // workspace layout (needs ~231 MB)
  float* h    = (float*)d_ws;                 // 26,214,400 f  (105 MB)
  float* prim = h + 26214400;                 //  2,359,296 f
  float* w2t  = prim + 2359296;               //  5,308,416 f
  u16*   U    = (u16*)(w2t + 5308416);        // 47,185,920 bf16 (94 MB)
  float* vbuf = (float*)(U + 47185920);       //     40,960 f
  float* cbuf = vbuf + 40960;                 //     11,520 f
  float* bij  = cbuf + 11520;                 //     11,520 f
  float* part = bij + 11520;                  //     92,160 f

  hipMemsetAsync(bij, 0, 11520 * sizeof(float), stream);

  conv1_kernel<<<dim3(256, 2), 256, 0, stream>>>(x, w1, b1, h);
  w2t_kernel<<<dim3(648, 8), 256, 0, stream>>>(w2, w2t);
  conv2_kernel<<<dim3(256, 2), 256, 0, stream>>>(h, w2t, b2, prim);
  uhat_kernel<<<1152, 256, 0, stream>>>(prim, W, Wb, U);

  for (int r = 0; r < 3; ++r) {
    softmax_kernel<<<10, 256, 0, stream>>>(bij, cbuf);
    vpass_kernel<<<dim3(256, 10), 256, 0, stream>>>(U, cbuf, vbuf);
    squash_kernel<<<10, 256, 0, stream>>>(vbuf, out, r == 2 ? 1 : 0);
    if (r < 2) {
      bij_partial_kernel<<<dim3(5, 10, 8), 256, 0, stream>>>(U, vbuf, part);
      bij_reduce_kernel<<<45, 256, 0, stream>>>(part, bij);
    }
  }
}

// Round 2
// 749.818 us; speedup vs baseline: 3.7381x; 3.7381x over previous
//
#include <hip/hip_runtime.h>
#include <hip/hip_bf16.h>

#define DI __device__ __forceinline__

typedef unsigned int u32;
typedef unsigned short u16;
typedef __attribute__((ext_vector_type(8))) short short8;
typedef __attribute__((ext_vector_type(4))) float f32x4;

DI float bf2f_lo(u32 u) { union { u32 x; float f; } t; t.x = u << 16; return t.f; }
DI float bf2f_hi(u32 u) { union { u32 x; float f; } t; t.x = u & 0xffff0000u; return t.f; }
DI u16 f2bf(float f) {
  union { float f; u32 x; } t; t.f = f;
  u32 x = t.x;
  u32 r = (x + 0x7fffu + ((x >> 16) & 1u)) >> 16;   // RNE
  return (u16)r;
}

typedef __attribute__((address_space(3))) u32 lds_u32;
typedef const __attribute__((address_space(1))) u32 gbl_u32;
DI void gl_lds16(const u16* g, u16* l) {
  __builtin_amdgcn_global_load_lds((gbl_u32*)(const void*)g, (lds_u32*)(void*)l, 16, 0, 0);
}

// ---------------- conv1: x[256,1,28,28] -> hT[b][y][x][ic] bf16 ----------------
__global__ __launch_bounds__(256) void conv1_kernel(
    const float* __restrict__ x, const float* __restrict__ w1,
    const float* __restrict__ b1, u16* __restrict__ hT) {
  __shared__ float xs[784];
  __shared__ float ws[10368]; // 128 oc * 81
  int b = blockIdx.x, oh = blockIdx.y, tid = threadIdx.x;
  const float* xb = x + (size_t)b * 784;
  for (int i = tid; i < 784; i += 256) xs[i] = xb[i];
  for (int i = tid; i < 10368; i += 256) ws[i] = w1[(size_t)oh * 10368 + i];
  __syncthreads();
  int ocl = tid & 127, yh = tid >> 7;
  int oc = oh * 128 + ocl;
  const float* w = ws + ocl * 81;
  float bias = b1[oc];
  u16* hb = hT + (size_t)b * 102400;
  for (int y = yh * 10; y < yh * 10 + 10; ++y) {
    float acc[20];
#pragma unroll
    for (int i = 0; i < 20; ++i) acc[i] = bias;
    for (int ky = 0; ky < 9; ++ky) {
      float wr[9];
#pragma unroll
      for (int i = 0; i < 9; ++i) wr[i] = w[ky * 9 + i];
      float xr[28];
#pragma unroll
      for (int i = 0; i < 28; ++i) xr[i] = xs[(y + ky) * 28 + i];
#pragma unroll
      for (int xx = 0; xx < 20; ++xx) {
#pragma unroll
        for (int kx = 0; kx < 9; ++kx) acc[xx] += xr[xx + kx] * wr[kx];
      }
    }
#pragma unroll
    for (int xx = 0; xx < 20; ++xx) hb[(y * 20 + xx) * 256 + oc] = f2bf(acc[xx]);
  }
}

// ---------------- weight transform: w2[oc][ic*81+tap] -> w2bT[tap][oc][ic] bf16 ----------------
__global__ __launch_bounds__(256) void w2b_kernel(
    const float* __restrict__ w2, u16* __restrict__ w2bT) {
  __shared__ float ws[5184]; // 64 ic * 81 taps
  int oc = blockIdx.x, tid = threadIdx.x;
  for (int ch = 0; ch < 4; ++ch) {
    __syncthreads();
    for (int t = tid; t < 5184; t += 256) ws[t] = w2[(size_t)oc * 20736 + ch * 5184 + t];
    __syncthreads();
    for (int t = tid; t < 5184; t += 256) {
      int tap = t >> 6, icl = t & 63;
      w2bT[((size_t)tap * 256 + oc) * 256 + ch * 64 + icl] = f2bf(ws[icl * 81 + tap]);
    }
  }
}

// ---------------- conv2 as implicit-GEMM MFMA ----------------
// C[row=b*36+p][oc] = sum_{tap,ic} hT[b][y(row,tap)][x(row,tap)][ic] * w2bT[tap][oc][ic]
// grid (72 rowblocks, 2 colblocks, 4 tap-slices); 256 thr = 4 waves, each 64x64.
__global__ __launch_bounds__(256) void conv2_mfma_kernel(
    const u16* __restrict__ hT, const u16* __restrict__ w2bT,
    float* __restrict__ pp) {
  __shared__ u16 Ab[2][8192]; // [128 rows][64 k] bf16, 16 KB each
  __shared__ u16 Bb[2][8192]; // [128 oc][64 k]
  int rb = blockIdx.x, cb = blockIdx.y, ks = blockIdx.z;
  int tid = threadIdx.x;
  int wid = tid >> 6, lane = tid & 63;
  int oc0 = cb * 128;
  int tap0 = ks ? (20 * ks + 1) : 0;
  int ntap = ks ? 20 : 21;
  int nch = ntap * 4;

  // per-lane staging source pointers (rows constant across k-loop)
  const u16* rpA[4];
  const u16* rpB[4];
#pragma unroll
  for (int c = 0; c < 4; ++c) {
    int r = c * 32 + wid * 8 + (lane >> 3);
    int grow = rb * 128 + r;
    int b = grow / 36, p = grow % 36;
    int py = p / 6, px = p % 6;
    int swz = ((lane & 7) ^ (r & 7)) * 8; // XOR-swizzled source granule (elements)
    rpA[c] = hT + ((size_t)b * 400 + py * 40 + px * 2) * 256 + swz;
    rpB[c] = w2bT + ((size_t)(oc0 + r)) * 256 + swz;
  }

  f32x4 acc[4][4];
#pragma unroll
  for (int i = 0; i < 4; ++i)
#pragma unroll
    for (int j = 0; j < 4; ++j) acc[i][j] = (f32x4){0.f, 0.f, 0.f, 0.f};

  int wr = wid >> 1, wc = wid & 1;
  int l15 = lane & 15, lh = lane >> 4;

  // prologue: stage chunk 0 into buf 0
  {
    int tap = tap0;
    int tofsA = ((tap / 9) * 20 + (tap % 9)) * 256;
    size_t tofsB = (size_t)tap * 65536;
#pragma unroll
    for (int c = 0; c < 4; ++c) {
      gl_lds16(rpA[c] + tofsA, &Ab[0][(c * 32 + wid * 8) * 64]);
      gl_lds16(rpB[c] + tofsB, &Bb[0][(c * 32 + wid * 8) * 64]);
    }
  }

  for (int ch = 0; ch < nch; ++ch) {
    __syncthreads(); // drains vmcnt -> stage of current buf complete; prev compute done
    int buf = ch & 1;
    if (ch + 1 < nch) {
      int nc2 = ch + 1;
      int tap = tap0 + (nc2 >> 2);
      int ic0 = (nc2 & 3) << 6;
      int tofsA = ((tap / 9) * 20 + (tap % 9)) * 256 + ic0;
      size_t tofsB = (size_t)tap * 65536 + ic0;
#pragma unroll
      for (int c = 0; c < 4; ++c) {
        gl_lds16(rpA[c] + tofsA, &Ab[buf ^ 1][(c * 32 + wid * 8) * 64]);
        gl_lds16(rpB[c] + tofsB, &Bb[buf ^ 1][(c * 32 + wid * 8) * 64]);
      }
    }
#pragma unroll
    for (int kk = 0; kk < 2; ++kk) {
      int g = kk * 4 + lh;
      short8 ar[4], br[4];
#pragma unroll
      for (int mi = 0; mi < 4; ++mi) {
        int row = wr * 64 + mi * 16 + l15;
        ar[mi] = *(const short8*)&Ab[buf][row * 64 + ((g ^ (row & 7)) * 8)];
      }
#pragma unroll
      for (int ni = 0; ni < 4; ++ni) {
        int row = wc * 64 + ni * 16 + l15;
        br[ni] = *(const short8*)&Bb[buf][row * 64 + ((g ^ (row & 7)) * 8)];
      }
#pragma unroll
      for (int mi = 0; mi < 4; ++mi)
#pragma unroll
        for (int ni = 0; ni < 4; ++ni)
          acc[mi][ni] = __builtin_amdgcn_mfma_f32_16x16x32_bf16(ar[mi], br[ni], acc[mi][ni], 0, 0, 0);
    }
  }

  // epilogue: per-kslice partials (deterministic; reduced in uhat)
  float* base = pp + (size_t)ks * 2359296;
#pragma unroll
  for (int mi = 0; mi < 4; ++mi) {
#pragma unroll
    for (int reg = 0; reg < 4; ++reg) {
      int m = wr * 64 + mi * 16 + lh * 4 + reg;
      int grow = rb * 128 + m;
      int b = grow / 36, p = grow % 36;
#pragma unroll
      for (int ni = 0; ni < 4; ++ni) {
        int oc = oc0 + wc * 64 + ni * 16 + l15;
        base[(size_t)b * 9216 + oc * 36 + p] = acc[mi][ni][reg];
      }
    }
  }
}

// ---------------- u_hat: prim partials -> U[b][m=loc*10+i][o] (bf16) ----------------
__global__ __launch_bounds__(256) void uhat_kernel(
    const float* __restrict__ pp, const float* __restrict__ b2,
    const float* __restrict__ W, const float* __restrict__ Wb, u16* __restrict__ U) {
  __shared__ float Ws[1280];  // [i][o][c] for this loc
  __shared__ float Wbs[160];  // [i][o]
  __shared__ float ps[2048];  // [b][c]
  int loc = blockIdx.x, tid = threadIdx.x;
  int j = loc / 36, k = (loc / 6) % 6, l = loc % 6;
  size_t wbase = (size_t)j * 4608 + k * 768 + l * 128;
  for (int t = tid; t < 1280; t += 256) {
    int i = t >> 7, rem = t & 127;
    Ws[t] = W[(size_t)i * 147456 + wbase + rem];
  }
  for (int t = tid; t < 160; t += 256) {
    int i = t / 16, o = t & 15;
    Wbs[t] = Wb[(size_t)i * 18432 + j * 576 + k * 96 + l * 16 + o];
  }
  int pbase = j * 288 + k * 48 + l * 8;
  for (int t = tid; t < 2048; t += 256) {
    int bb = t >> 3, c = t & 7;
    int flat = pbase + c;
    float val = b2[flat / 36];
#pragma unroll
    for (int kss = 0; kss < 4; ++kss)
      val += pp[(size_t)kss * 2359296 + (size_t)bb * 9216 + flat];
    ps[t] = val;
  }
  __syncthreads();
  int b = tid;
  float pr[8];
#pragma unroll
  for (int c = 0; c < 8; ++c) pr[c] = ps[b * 8 + c];
  u16* Ub = U + ((size_t)b * 11520 + (size_t)loc * 10) * 16;
  for (int i = 0; i < 10; ++i) {
#pragma unroll
    for (int o = 0; o < 16; ++o) {
      float a = Wbs[i * 16 + o];
#pragma unroll
      for (int c = 0; c < 8; ++c) a += pr[c] * Ws[i * 128 + o * 8 + c];
      Ub[i * 16 + o] = f2bf(a);
    }
  }
}

// ---------------- routing ----------------
__global__ __launch_bounds__(256) void softmax_kernel(
    const float* __restrict__ bij, float* __restrict__ c) {
  __shared__ float red[256];
  int i = blockIdx.x, tid = threadIdx.x;
  float m = -1e30f;
  for (int n = tid; n < 1152; n += 256) m = fmaxf(m, bij[i * 1152 + n]);
  red[tid] = m; __syncthreads();
  for (int s = 128; s > 0; s >>= 1) { if (tid < s) red[tid] = fmaxf(red[tid], red[tid + s]); __syncthreads(); }
  m = red[0]; __syncthreads();
  float sum = 0.f;
  for (int n = tid; n < 1152; n += 256) sum += expf(bij[i * 1152 + n] - m);
  red[tid] = sum; __syncthreads();
  for (int s = 128; s > 0; s >>= 1) { if (tid < s) red[tid] += red[tid + s]; __syncthreads(); }
  float inv = 1.0f / red[0];
  for (int n = tid; n < 1152; n += 256) c[i * 1152 + n] = expf(bij[i * 1152 + n] - m) * inv;
}

// v[b,i,k] = sum_n c[i,n] * U[b][i*1152+n][k]
__global__ __launch_bounds__(256) void vpass_kernel(
    const u16* __restrict__ U, const float* __restrict__ c, float* __restrict__ v) {
  __shared__ float red[256][17];
  int b = blockIdx.x, i = blockIdx.y, tid = threadIdx.x;
  float acc[16];
#pragma unroll
  for (int k = 0; k < 16; ++k) acc[k] = 0.f;
  const u16* Ub = U + ((size_t)b * 11520 + (size_t)i * 1152) * 16;
  for (int n = tid; n < 1152; n += 256) {
    float cv = c[i * 1152 + n];
    const uint4* row = (const uint4*)(Ub + (size_t)n * 16);
    uint4 r0 = row[0], r1 = row[1];
    u32 rr[8] = {r0.x, r0.y, r0.z, r0.w, r1.x, r1.y, r1.z, r1.w};
#pragma unroll
    for (int q = 0; q < 8; ++q) {
      acc[2 * q]     += cv * bf2f_lo(rr[q]);
      acc[2 * q + 1] += cv * bf2f_hi(rr[q]);
    }
  }
#pragma unroll
  for (int k = 0; k < 16; ++k) red[tid][k] = acc[k];
  __syncthreads();
  for (int s = 128; s > 0; s >>= 1) {
    if (tid < s) {
#pragma unroll
      for (int k = 0; k < 16; ++k) red[tid][k] += red[tid + s][k];
    }
    __syncthreads();
  }
  if (tid < 16) v[(size_t)b * 160 + i * 16 + tid] = red[0][tid];
}

// squash over whole batch per class; optionally emit final output [i][b][k]
__global__ __launch_bounds__(256) void squash_kernel(
    float* __restrict__ v, float* __restrict__ out, int finalf) {
  __shared__ float red[256];
  int i = blockIdx.x, tid = threadIdx.x;
  float s = 0.f;
  for (int t = tid; t < 4096; t += 256) {
    int bb = t >> 4, k = t & 15;
    float xv = v[bb * 160 + i * 16 + k];
    s += xv * xv;
  }
  red[tid] = s; __syncthreads();
  for (int st = 128; st > 0; st >>= 1) { if (tid < st) red[tid] += red[tid + st]; __syncthreads(); }
  float nrm = sqrtf(red[0]);
  float n2 = nrm * nrm;
  float scale = (n2 / (1.f + n2)) / nrm;
  for (int t = tid; t < 4096; t += 256) {
    int bb = t >> 4, k = t & 15;
    float xv = v[bb * 160 + i * 16 + k] * scale;
    if (finalf) out[(size_t)i * 4096 + bb * 16 + k] = xv;
    else v[bb * 160 + i * 16 + k] = xv;
  }
}

// partial bij update: part[bz][i][n] = sum_{b in chunk,k} U[b][i*1152+n][k]*v[b,i,k]
__global__ __launch_bounds__(256) void bij_partial_kernel(
    const u16* __restrict__ U, const float* __restrict__ v, float* __restrict__ part) {
  int nc = blockIdx.x, i = blockIdx.y, bz = blockIdx.z, tid = threadIdx.x;
  int n = nc * 256 + tid;
  if (n >= 1152) return;
  float s = 0.f;
  for (int bb = bz * 32; bb < bz * 32 + 32; ++bb) {
    const uint4* row = (const uint4*)(U + ((size_t)bb * 11520 + (size_t)i * 1152 + n) * 16);
    uint4 r0 = row[0], r1 = row[1];
    const float* vb = v + (size_t)bb * 160 + i * 16;
    u32 rr[8] = {r0.x, r0.y, r0.z, r0.w, r1.x, r1.y, r1.z, r1.w};
#pragma unroll
    for (int q = 0; q < 8; ++q) {
      s += bf2f_lo(rr[q]) * vb[2 * q];
      s += bf2f_hi(rr[q]) * vb[2 * q + 1];
    }
  }
  part[((size_t)bz * 10 + i) * 1152 + n] = s;
}

__global__ __launch_bounds__(256) void bij_reduce_kernel(
    const float* __restrict__ part, float* __restrict__ bij) {
  int idx = blockIdx.x * 256 + threadIdx.x;
  if (idx >= 11520) return;
  float s = bij[idx];
#pragma unroll
  for (int bz = 0; bz < 8; ++bz) s += part[(size_t)bz * 11520 + idx];
  bij[idx] = s;
}

extern "C" void kernel_launch(void* const* d_in, const int* in_sizes, int n_in,
                              void* d_out, int out_size, void* d_ws, size_t ws_size,
                              hipStream_t stream) {
  const float* x  = (const float*)d_in[0];
  const float* w1 = (const float*)d_in[1];
  const float* b1 = (const float*)d_in[2];
  const float* w2 = (const float*)d_in[3];
  const float* b2 = (const float*)d_in[4];
  const float* W  = (const float*)d_in[5];
  const float* Wb = (const float*)d_in[6];
  float* out = (float*)d_out;

  // workspace layout (~197 MB)
  u16*   hT   = (u16*)d_ws;                   // 26,214,400 bf16 (52.4 MB)
  u16*   w2bT = hT + 26214400;                //  5,308,416 bf16 (10.6 MB)
  float* pp   = (float*)(w2bT + 5308416);     //  4*2,359,296 f  (37.7 MB)
  u16*   U    = (u16*)(pp + 9437184);         // 47,185,920 bf16 (94.4 MB)
  float* vbuf = (float*)(U + 47185920);       //     40,960 f
  float* cbuf = vbuf + 40960;                 //     11,520 f
  float* bij  = cbuf + 11520;                 //     11,520 f
  float* part = bij + 11520;                  //     92,160 f

  hipMemsetAsync(bij, 0, 11520 * sizeof(float), stream);

  conv1_kernel<<<dim3(256, 2), 256, 0, stream>>>(x, w1, b1, hT);
  w2b_kernel<<<256, 256, 0, stream>>>(w2, w2bT);
  conv2_mfma_kernel<<<dim3(72, 2, 4), 256, 0, stream>>>(hT, w2bT, pp);
  uhat_kernel<<<1152, 256, 0, stream>>>(pp, b2, W, Wb, U);

  for (int r = 0; r < 3; ++r) {
    softmax_kernel<<<10, 256, 0, stream>>>(bij, cbuf);
    vpass_kernel<<<dim3(256, 10), 256, 0, stream>>>(U, cbuf, vbuf);
    squash_kernel<<<10, 256, 0, stream>>>(vbuf, out, r == 2 ? 1 : 0);
    if (r < 2) {
      bij_partial_kernel<<<dim3(5, 10, 8), 256, 0, stream>>>(U, vbuf, part);
      bij_reduce_kernel<<<45, 256, 0, stream>>>(part, bij);
    }
  }
}

// Round 3
// 526.067 us; speedup vs baseline: 5.3280x; 1.4253x over previous
//
#include <hip/hip_runtime.h>
#include <hip/hip_bf16.h>

#define DI __device__ __forceinline__

typedef unsigned int u32;
typedef unsigned short u16;
typedef __attribute__((ext_vector_type(8))) short short8;
typedef __attribute__((ext_vector_type(4))) float f32x4;

DI u16 f2bf(float f) {
  union { float f; u32 x; } t; t.f = f;
  u32 x = t.x;
  u32 r = (x + 0x7fffu + ((x >> 16) & 1u)) >> 16;   // RNE
  return (u16)r;
}

typedef __attribute__((address_space(3))) u32 lds_u32;
typedef const __attribute__((address_space(1))) u32 gbl_u32;
DI void gl_lds16(const u16* g, u16* l) {
  __builtin_amdgcn_global_load_lds((gbl_u32*)(const void*)g, (lds_u32*)(void*)l, 16, 0, 0);
}

// ---------------- conv1: x[256,1,28,28] -> hT[b][y][x][ic] bf16 ----------------
__global__ __launch_bounds__(256) void conv1_kernel(
    const float* __restrict__ x, const float* __restrict__ w1,
    const float* __restrict__ b1, u16* __restrict__ hT) {
  __shared__ float xs[784];
  __shared__ float ws[10368]; // 128 oc * 81
  int b = blockIdx.x, oh = blockIdx.y, tid = threadIdx.x;
  const float* xb = x + (size_t)b * 784;
  for (int i = tid; i < 784; i += 256) xs[i] = xb[i];
  for (int i = tid; i < 10368; i += 256) ws[i] = w1[(size_t)oh * 10368 + i];
  __syncthreads();
  int ocl = tid & 127, yh = tid >> 7;
  int oc = oh * 128 + ocl;
  const float* w = ws + ocl * 81;
  float bias = b1[oc];
  u16* hb = hT + (size_t)b * 102400;
  for (int y = yh * 10; y < yh * 10 + 10; ++y) {
    float acc[20];
#pragma unroll
    for (int i = 0; i < 20; ++i) acc[i] = bias;
    for (int ky = 0; ky < 9; ++ky) {
      float wr[9];
#pragma unroll
      for (int i = 0; i < 9; ++i) wr[i] = w[ky * 9 + i];
      float xr[28];
#pragma unroll
      for (int i = 0; i < 28; ++i) xr[i] = xs[(y + ky) * 28 + i];
#pragma unroll
      for (int xx = 0; xx < 20; ++xx) {
#pragma unroll
        for (int kx = 0; kx < 9; ++kx) acc[xx] += xr[xx + kx] * wr[kx];
      }
    }
#pragma unroll
    for (int xx = 0; xx < 20; ++xx) hb[(y * 20 + xx) * 256 + oc] = f2bf(acc[xx]);
  }
}

// ---------------- weight transform: w2[oc][ic*81+tap] -> w2bT[tap][oc][ic] bf16 ----------------
__global__ __launch_bounds__(256) void w2b_kernel(
    const float* __restrict__ w2, u16* __restrict__ w2bT) {
  __shared__ float ws[5184]; // 64 ic * 81 taps
  int oc = blockIdx.x, tid = threadIdx.x;
  for (int ch = 0; ch < 4; ++ch) {
    __syncthreads();
    for (int t = tid; t < 5184; t += 256) ws[t] = w2[(size_t)oc * 20736 + ch * 5184 + t];
    __syncthreads();
    for (int t = tid; t < 5184; t += 256) {
      int tap = t >> 6, icl = t & 63;
      w2bT[((size_t)tap * 256 + oc) * 256 + ch * 64 + icl] = f2bf(ws[icl * 81 + tap]);
    }
  }
}

// ---------------- conv2 as implicit-GEMM MFMA, rows ordered rr = p*256 + b ----------------
// writes pp[ks][oc*36+p][b] fp32 partials
__global__ __launch_bounds__(256) void conv2_mfma_kernel(
    const u16* __restrict__ hT, const u16* __restrict__ w2bT,
    float* __restrict__ pp) {
  __shared__ u16 Ab[2][8192]; // [128 rows][64 k]
  __shared__ u16 Bb[2][8192]; // [128 oc][64 k]
  int rb = blockIdx.x, cb = blockIdx.y, ks = blockIdx.z;
  int tid = threadIdx.x;
  int wid = tid >> 6, lane = tid & 63;
  int oc0 = cb * 128;
  int p = rb >> 1, bhalf = rb & 1;
  int py = p / 6, px = p % 6;
  int tap0 = ks ? (20 * ks + 1) : 0;
  int ntap = ks ? 20 : 21;
  int nch = ntap * 4;

  const u16* rpA[4];
  const u16* rpB[4];
#pragma unroll
  for (int c = 0; c < 4; ++c) {
    int r = c * 32 + wid * 8 + (lane >> 3);
    int b = bhalf * 128 + r;
    int swz = ((lane & 7) ^ (r & 7)) * 8;
    rpA[c] = hT + ((size_t)b * 400 + py * 40 + px * 2) * 256 + swz;
    rpB[c] = w2bT + ((size_t)(oc0 + r)) * 256 + swz;
  }

  f32x4 acc[4][4];
#pragma unroll
  for (int i = 0; i < 4; ++i)
#pragma unroll
    for (int j = 0; j < 4; ++j) acc[i][j] = (f32x4){0.f, 0.f, 0.f, 0.f};

  int wr = wid >> 1, wc = wid & 1;
  int l15 = lane & 15, lh = lane >> 4;

  {
    int tap = tap0;
    int tofsA = ((tap / 9) * 20 + (tap % 9)) * 256;
    size_t tofsB = (size_t)tap * 65536;
#pragma unroll
    for (int c = 0; c < 4; ++c) {
      gl_lds16(rpA[c] + tofsA, &Ab[0][(c * 32 + wid * 8) * 64]);
      gl_lds16(rpB[c] + tofsB, &Bb[0][(c * 32 + wid * 8) * 64]);
    }
  }

  for (int ch = 0; ch < nch; ++ch) {
    __syncthreads();
    int buf = ch & 1;
    if (ch + 1 < nch) {
      int nc2 = ch + 1;
      int tap = tap0 + (nc2 >> 2);
      int ic0 = (nc2 & 3) << 6;
      int tofsA = ((tap / 9) * 20 + (tap % 9)) * 256 + ic0;
      size_t tofsB = (size_t)tap * 65536 + ic0;
#pragma unroll
      for (int c = 0; c < 4; ++c) {
        gl_lds16(rpA[c] + tofsA, &Ab[buf ^ 1][(c * 32 + wid * 8) * 64]);
        gl_lds16(rpB[c] + tofsB, &Bb[buf ^ 1][(c * 32 + wid * 8) * 64]);
      }
    }
#pragma unroll
    for (int kk = 0; kk < 2; ++kk) {
      int g = kk * 4 + lh;
      short8 ar[4], br[4];
#pragma unroll
      for (int mi = 0; mi < 4; ++mi) {
        int row = wr * 64 + mi * 16 + l15;
        ar[mi] = *(const short8*)&Ab[buf][row * 64 + ((g ^ (row & 7)) * 8)];
      }
#pragma unroll
      for (int ni = 0; ni < 4; ++ni) {
        int row = wc * 64 + ni * 16 + l15;
        br[ni] = *(const short8*)&Bb[buf][row * 64 + ((g ^ (row & 7)) * 8)];
      }
#pragma unroll
      for (int mi = 0; mi < 4; ++mi)
#pragma unroll
        for (int ni = 0; ni < 4; ++ni)
          acc[mi][ni] = __builtin_amdgcn_mfma_f32_16x16x32_bf16(ar[mi], br[ni], acc[mi][ni], 0, 0, 0);
    }
  }

  // epilogue: pp[ks][oc*36+p][b] ; 4 consecutive regs+4 lh fill 16 consecutive b
  float* ppk = pp + (size_t)ks * 2359296 + (size_t)p * 256 + bhalf * 128;
#pragma unroll
  for (int mi = 0; mi < 4; ++mi) {
#pragma unroll
    for (int reg = 0; reg < 4; ++reg) {
      int m = wr * 64 + mi * 16 + lh * 4 + reg;
#pragma unroll
      for (int ni = 0; ni < 4; ++ni) {
        int oc = oc0 + wc * 64 + ni * 16 + l15;
        ppk[(size_t)oc * 9216 + m] = acc[mi][ni][reg];
      }
    }
  }
}

// ---------------- split-K reduce + bias: prim2T[flat][b] = sum_ks pp + b2[flat/36] ----------------
__global__ __launch_bounds__(256) void prim_reduce_kernel(
    const float* __restrict__ pp, const float* __restrict__ b2,
    float* __restrict__ prim2T) {
  int e = blockIdx.x * 256 + threadIdx.x;   // float4 index, 589824 total
  int flat = e >> 6;
  float bias = b2[flat / 36];
  const float4* p0 = (const float4*)pp;
  float4 a = p0[e], b = p0[589824 + e], c = p0[2 * 589824 + e], d = p0[3 * 589824 + e];
  float4 r;
  r.x = a.x + b.x + c.x + d.x + bias;
  r.y = a.y + b.y + c.y + d.y + bias;
  r.z = a.z + b.z + c.z + d.z + bias;
  r.w = a.w + b.w + c.w + d.w + bias;
  ((float4*)prim2T)[e] = r;
}

// ---------------- softmax over n per class + cb[i][k] = sum_n c*Wb ----------------
__global__ __launch_bounds__(256) void softmax_cb_kernel(
    const float* __restrict__ bij, const float* __restrict__ Wb,
    float* __restrict__ c, float* __restrict__ cb) {
  __shared__ float red[256];
  __shared__ float red2[256][17];
  int i = blockIdx.x, tid = threadIdx.x;
  float m = -1e30f;
  for (int n = tid; n < 1152; n += 256) m = fmaxf(m, bij[i * 1152 + n]);
  red[tid] = m; __syncthreads();
  for (int s = 128; s > 0; s >>= 1) { if (tid < s) red[tid] = fmaxf(red[tid], red[tid + s]); __syncthreads(); }
  m = red[0]; __syncthreads();
  float sum = 0.f;
  for (int n = tid; n < 1152; n += 256) sum += expf(bij[i * 1152 + n] - m);
  red[tid] = sum; __syncthreads();
  for (int s = 128; s > 0; s >>= 1) { if (tid < s) red[tid] += red[tid + s]; __syncthreads(); }
  float inv = 1.0f / red[0];
  float acc[16];
#pragma unroll
  for (int k = 0; k < 16; ++k) acc[k] = 0.f;
  for (int n = tid; n < 1152; n += 256) {
    float cv = expf(bij[i * 1152 + n] - m) * inv;
    c[i * 1152 + n] = cv;
    int mm = i * 1152 + n;
    const float* wb = Wb + (size_t)(mm % 10) * 18432 + (size_t)(mm / 10) * 16;
#pragma unroll
    for (int k = 0; k < 16; ++k) acc[k] += cv * wb[k];
  }
#pragma unroll
  for (int k = 0; k < 16; ++k) red2[tid][k] = acc[k];
  __syncthreads();
  for (int s = 128; s > 0; s >>= 1) {
    if (tid < s) {
#pragma unroll
      for (int k = 0; k < 16; ++k) red2[tid][k] += red2[tid + s][k];
    }
    __syncthreads();
  }
  if (tid < 16) cb[i * 16 + tid] = red2[0][tid];
}

// ---------------- CW[flat][slot][k] = sum_io c[i_lo+slot, n]*W[io,loc,k,c] ----------------
__global__ __launch_bounds__(256) void cw_build_kernel(
    const float* __restrict__ c, const float* __restrict__ W,
    float* __restrict__ CW) {
  int blk = blockIdx.x, tid = threadIdx.x;
  int loc_l = tid >> 5, slot = (tid >> 4) & 1, k = tid & 15;
  int loc = blk * 8 + loc_l;
  int i_lo = (loc * 10) / 1152;
  int i_cls = i_lo + slot;
  float acc[8];
#pragma unroll
  for (int cc = 0; cc < 8; ++cc) acc[cc] = 0.f;
  if (i_cls < 10) {
    for (int io = 0; io < 10; ++io) {
      int mm = loc * 10 + io;
      if (mm / 1152 == i_cls) {
        float cv = c[i_cls * 1152 + mm % 1152];
        const float* wrow = W + (size_t)io * 147456 + (size_t)loc * 128 + k * 8;
        float4 w0 = *(const float4*)wrow;
        float4 w1 = *(const float4*)(wrow + 4);
        acc[0] += cv * w0.x; acc[1] += cv * w0.y; acc[2] += cv * w0.z; acc[3] += cv * w0.w;
        acc[4] += cv * w1.x; acc[5] += cv * w1.y; acc[6] += cv * w1.z; acc[7] += cv * w1.w;
      }
    }
  }
#pragma unroll
  for (int cc = 0; cc < 8; ++cc)
    CW[(size_t)(loc * 8 + cc) * 32 + slot * 16 + k] = acc[cc];
}

// ---------------- vgemm: vp[ch][i][b][k] = sum_{loc in chunk} prim2T*CW ----------------
__global__ __launch_bounds__(256) void vgemm_kernel(
    const float* __restrict__ prim2T, const float* __restrict__ CW,
    float* __restrict__ vp) {
  __shared__ float cws[1920]; // [15 loc][8 c][16 k]
  int ch = blockIdx.x, i = blockIdx.y, tid = threadIdx.x;
  int loc_min = (i * 1152) / 10;
  int loc_max = ((i + 1) * 1152 - 1) / 10;
  int lc0 = loc_min + ch * 15;
  for (int t = tid; t < 1920; t += 256) {
    int ll = t >> 7, rem = t & 127;
    int loc = lc0 + ll;
    float v = 0.f;
    if (loc <= loc_max) {
      int slot = i - (loc * 10) / 1152;
      int cc = rem >> 4, k = rem & 15;
      v = CW[(size_t)(loc * 8 + cc) * 32 + slot * 16 + k];
    }
    cws[t] = v;
  }
  __syncthreads();
  float acc[16];
#pragma unroll
  for (int k = 0; k < 16; ++k) acc[k] = 0.f;
  for (int ll = 0; ll < 15; ++ll) {
    int loc = lc0 + ll;
    if (loc > loc_max) break;
    const float* pr = prim2T + (size_t)loc * 8 * 256 + tid;
    const float* cw = cws + ll * 128;
#pragma unroll
    for (int cc = 0; cc < 8; ++cc) {
      float pvv = pr[cc * 256];
      float4 a0 = *(const float4*)&cw[cc * 16];
      float4 a1 = *(const float4*)&cw[cc * 16 + 4];
      float4 a2 = *(const float4*)&cw[cc * 16 + 8];
      float4 a3 = *(const float4*)&cw[cc * 16 + 12];
      acc[0] += pvv * a0.x; acc[1] += pvv * a0.y; acc[2] += pvv * a0.z; acc[3] += pvv * a0.w;
      acc[4] += pvv * a1.x; acc[5] += pvv * a1.y; acc[6] += pvv * a1.z; acc[7] += pvv * a1.w;
      acc[8] += pvv * a2.x; acc[9] += pvv * a2.y; acc[10] += pvv * a2.z; acc[11] += pvv * a2.w;
      acc[12] += pvv * a3.x; acc[13] += pvv * a3.y; acc[14] += pvv * a3.z; acc[15] += pvv * a3.w;
    }
  }
  float* dst = vp + ((size_t)(ch * 10 + i) * 256 + tid) * 16;
#pragma unroll
  for (int k = 0; k < 16; ++k) dst[k] = acc[k];
}

// ---------------- squash_combine: v = squash(sum_ch vp + cb); sv; out on final ----------------
__global__ __launch_bounds__(256) void squash_combine_kernel(
    const float* __restrict__ vp, const float* __restrict__ cb,
    float* __restrict__ v2, float* __restrict__ sv, float* __restrict__ out, int finalf) {
  __shared__ float red[256];
  __shared__ float red2[256][17];
  int i = blockIdx.x, tid = threadIdx.x;
  float vpre[16];
#pragma unroll
  for (int k = 0; k < 16; ++k) vpre[k] = cb[i * 16 + k];
  for (int ch = 0; ch < 8; ++ch) {
    const float4* src = (const float4*)(vp + ((size_t)(ch * 10 + i) * 256 + tid) * 16);
#pragma unroll
    for (int q = 0; q < 4; ++q) {
      float4 a = src[q];
      vpre[q * 4 + 0] += a.x; vpre[q * 4 + 1] += a.y; vpre[q * 4 + 2] += a.z; vpre[q * 4 + 3] += a.w;
    }
  }
  float ss = 0.f;
#pragma unroll
  for (int k = 0; k < 16; ++k) { ss += vpre[k] * vpre[k]; red2[tid][k] = vpre[k]; }
  red[tid] = ss; __syncthreads();
  for (int s = 128; s > 0; s >>= 1) {
    if (tid < s) {
      red[tid] += red[tid + s];
#pragma unroll
      for (int k = 0; k < 16; ++k) red2[tid][k] += red2[tid + s][k];
    }
    __syncthreads();
  }
  float nrm = sqrtf(red[0]);
  float n2 = nrm * nrm;
  float scale = nrm / (1.f + n2);
  if (tid < 16) sv[i * 16 + tid] = scale * red2[0][tid];
  float* dst = (finalf ? out : v2) + (size_t)i * 4096 + tid * 16;
#pragma unroll
  for (int k = 0; k < 16; ++k) dst[k] = vpre[k] * scale;
}

// ---------------- pv: P[flat][slot][k] = sum_b prim2T[flat][b]*v2[cls][b][k] ----------------
__global__ __launch_bounds__(256) void pv_kernel(
    const float* __restrict__ prim2T, const float* __restrict__ v2,
    float* __restrict__ P) {
  __shared__ float ps[64 * 260];      // [flat_l][b] padded
  __shared__ float vs[2 * 16 * 260];  // [cl][k][b] padded
  int blk = blockIdx.x, tid = threadIdx.x;
  int loc0 = blk * 8;
  int I = (loc0 * 10) / 1152;
  for (int t = tid; t < 4096; t += 256) {
    int row = t >> 6, seg = t & 63;
    float4 a = *(const float4*)(prim2T + (size_t)(loc0 * 8 + row) * 256 + seg * 4);
    *(float4*)&ps[row * 260 + seg * 4] = a;
  }
  for (int cl = 0; cl < 2; ++cl) {
    int cls = I + cl;
    for (int t = tid; t < 4096; t += 256) {
      int b = t >> 4, k = t & 15;
      float val = (cls <= 9) ? v2[(size_t)cls * 4096 + t] : 0.f;
      vs[(cl * 16 + k) * 260 + b] = val;
    }
  }
  __syncthreads();
  int k = tid & 15, fs = tid >> 4;
  const float4* ps4 = (const float4*)ps;
  const float4* vs4 = (const float4*)vs;
#pragma unroll
  for (int q = 0; q < 8; ++q) {
    int flat_l = fs * 4 + (q & 3);
    int slot = q >> 2;
    int loc = loc0 + (flat_l >> 3);
    int cls = (loc * 10) / 1152 + slot;
    int cl_idx = cls - I;
    if (cl_idx <= 1 && cls <= 9) {
      float a = 0.f;
      int bp = flat_l * 65, bv = (cl_idx * 16 + k) * 65;
      for (int b4 = 0; b4 < 64; ++b4) {
        float4 p4 = ps4[bp + b4];
        float4 w4 = vs4[bv + b4];
        a += p4.x * w4.x + p4.y * w4.y + p4.z * w4.z + p4.w * w4.w;
      }
      P[(size_t)(loc0 * 8 + flat_l) * 32 + slot * 16 + k] = a;
    }
  }
}

// ---------------- bij_assemble: bij[m] += sum_{c,k} W*P + Wb.sv ----------------
__global__ __launch_bounds__(256) void bij_assemble_kernel(
    const float* __restrict__ W, const float* __restrict__ Wb,
    const float* __restrict__ P, const float* __restrict__ sv,
    float* __restrict__ bij) {
  int m = blockIdx.x * 256 + threadIdx.x;
  int i = m / 1152, loc = m / 10, io = m % 10;
  int slot = i - (loc * 10) / 1152;
  const float* wrow = W + (size_t)io * 147456 + (size_t)loc * 128;
  const float* prow = P + (size_t)(loc * 8) * 32 + slot * 16;
  float s = 0.f;
#pragma unroll
  for (int k = 0; k < 16; ++k) {
    float4 w0 = *(const float4*)(wrow + k * 8);
    float4 w1 = *(const float4*)(wrow + k * 8 + 4);
    s += w0.x * prow[0 * 32 + k] + w0.y * prow[1 * 32 + k] + w0.z * prow[2 * 32 + k] + w0.w * prow[3 * 32 + k];
    s += w1.x * prow[4 * 32 + k] + w1.y * prow[5 * 32 + k] + w1.z * prow[6 * 32 + k] + w1.w * prow[7 * 32 + k];
  }
  const float* wbr = Wb + (size_t)io * 18432 + (size_t)loc * 16;
  const float* svr = sv + i * 16;
#pragma unroll
  for (int k = 0; k < 16; ++k) s += wbr[k] * svr[k];
  bij[m] += s;
}

extern "C" void kernel_launch(void* const* d_in, const int* in_sizes, int n_in,
                              void* d_out, int out_size, void* d_ws, size_t ws_size,
                              hipStream_t stream) {
  const float* x  = (const float*)d_in[0];
  const float* w1 = (const float*)d_in[1];
  const float* b1 = (const float*)d_in[2];
  const float* w2 = (const float*)d_in[3];
  const float* b2 = (const float*)d_in[4];
  const float* W  = (const float*)d_in[5];
  const float* Wb = (const float*)d_in[6];
  float* out = (float*)d_out;

  // workspace layout (~114 MB)
  u16*   hT     = (u16*)d_ws;                    // 26,214,400 u16
  u16*   w2bT   = hT + 26214400;                 //  5,308,416 u16
  float* pp     = (float*)(w2bT + 5308416);      //  9,437,184 f
  float* prim2T = pp + 9437184;                  //  2,359,296 f
  float* CW     = prim2T + 2359296;              //    294,912 f
  float* P      = CW + 294912;                   //    294,912 f
  float* vp     = P + 294912;                    //    327,680 f
  float* v2     = vp + 327680;                   //     40,960 f
  float* cbuf   = v2 + 40960;                    //     11,520 f
  float* bij    = cbuf + 11520;                  //     11,520 f
  float* cb     = bij + 11520;                   //        160 f
  float* sv     = cb + 160;                      //        160 f

  hipMemsetAsync(bij, 0, 11520 * sizeof(float), stream);

  conv1_kernel<<<dim3(256, 2), 256, 0, stream>>>(x, w1, b1, hT);
  w2b_kernel<<<256, 256, 0, stream>>>(w2, w2bT);
  conv2_mfma_kernel<<<dim3(72, 2, 4), 256, 0, stream>>>(hT, w2bT, pp);
  prim_reduce_kernel<<<2304, 256, 0, stream>>>(pp, b2, prim2T);

  for (int r = 0; r < 3; ++r) {
    softmax_cb_kernel<<<10, 256, 0, stream>>>(bij, Wb, cbuf, cb);
    cw_build_kernel<<<144, 256, 0, stream>>>(cbuf, W, CW);
    vgemm_kernel<<<dim3(8, 10), 256, 0, stream>>>(prim2T, CW, vp);
    squash_combine_kernel<<<10, 256, 0, stream>>>(vp, cb, v2, sv, out, r == 2 ? 1 : 0);
    if (r < 2) {
      pv_kernel<<<144, 256, 0, stream>>>(prim2T, v2, P);
      bij_assemble_kernel<<<45, 256, 0, stream>>>(W, Wb, P, sv, bij);
    }
  }
}

// Round 4
// 411.479 us; speedup vs baseline: 6.8117x; 1.2785x over previous
//
#include <hip/hip_runtime.h>
#include <hip/hip_bf16.h>

#define DI __device__ __forceinline__

typedef unsigned int u32;
typedef unsigned short u16;
typedef __attribute__((ext_vector_type(8))) short short8;
typedef __attribute__((ext_vector_type(4))) float f32x4;

DI u16 f2bf(float f) {
  union { float f; u32 x; } t; t.f = f;
  u32 x = t.x;
  u32 r = (x + 0x7fffu + ((x >> 16) & 1u)) >> 16;   // RNE
  return (u16)r;
}

typedef __attribute__((address_space(3))) u32 lds_u32;
typedef const __attribute__((address_space(1))) u32 gbl_u32;
DI void gl_lds16(const u16* g, u16* l) {
  __builtin_amdgcn_global_load_lds((gbl_u32*)(const void*)g, (lds_u32*)(void*)l, 16, 0, 0);
}

// ---------------- conv1: x[256,1,28,28] -> hT[b][y][x][ic] bf16 ----------------
__global__ __launch_bounds__(256) void conv1_kernel(
    const float* __restrict__ x, const float* __restrict__ w1,
    const float* __restrict__ b1, u16* __restrict__ hT) {
  __shared__ float xs[784];
  __shared__ float ws[10368]; // 128 oc * 81
  int b = blockIdx.x, oh = blockIdx.y, tid = threadIdx.x;
  const float* xb = x + (size_t)b * 784;
  for (int i = tid; i < 784; i += 256) xs[i] = xb[i];
  for (int i = tid; i < 10368; i += 256) ws[i] = w1[(size_t)oh * 10368 + i];
  __syncthreads();
  int ocl = tid & 127, yh = tid >> 7;
  int oc = oh * 128 + ocl;
  const float* w = ws + ocl * 81;
  float bias = b1[oc];
  u16* hb = hT + (size_t)b * 102400;
  for (int y = yh * 10; y < yh * 10 + 10; ++y) {
    float acc[20];
#pragma unroll
    for (int i = 0; i < 20; ++i) acc[i] = bias;
    for (int ky = 0; ky < 9; ++ky) {
      float wr[9];
#pragma unroll
      for (int i = 0; i < 9; ++i) wr[i] = w[ky * 9 + i];
      float xr[28];
#pragma unroll
      for (int i = 0; i < 28; ++i) xr[i] = xs[(y + ky) * 28 + i];
#pragma unroll
      for (int xx = 0; xx < 20; ++xx) {
#pragma unroll
        for (int kx = 0; kx < 9; ++kx) acc[xx] += xr[xx + kx] * wr[kx];
      }
    }
#pragma unroll
    for (int xx = 0; xx < 20; ++xx) hb[(y * 20 + xx) * 256 + oc] = f2bf(acc[xx]);
  }
}

// ---------------- weight transform: w2[oc][ic*81+tap] -> w2bT[tap][oc][ic] bf16 ----------------
__global__ __launch_bounds__(256) void w2b_kernel(
    const float* __restrict__ w2, u16* __restrict__ w2bT) {
  __shared__ float ws[5184]; // 64 ic * 81 taps
  int oc = blockIdx.x, tid = threadIdx.x;
  for (int ch = 0; ch < 4; ++ch) {
    __syncthreads();
    for (int t = tid; t < 5184; t += 256) ws[t] = w2[(size_t)oc * 20736 + ch * 5184 + t];
    __syncthreads();
    for (int t = tid; t < 5184; t += 256) {
      int tap = t >> 6, icl = t & 63;
      w2bT[((size_t)tap * 256 + oc) * 256 + ch * 64 + icl] = f2bf(ws[icl * 81 + tap]);
    }
  }
}

// ---------------- conv2: 256x256 tile per block, one output pixel p per block ----------------
// C[b][oc] for fixed p; K sliced 7 ways interleaved (tap = j*7+ks). 8 waves (2x4).
// writes pp[ks][oc][p][b] fp32 partials
__global__ __launch_bounds__(512, 2) void conv2_mfma_kernel(
    const u16* __restrict__ hT, const u16* __restrict__ w2bT,
    float* __restrict__ pp) {
  __shared__ u16 Ab[2][16384]; // [256 b][64 k]
  __shared__ u16 Bb[2][16384]; // [256 oc][64 k]
  int p = blockIdx.x, ks = blockIdx.y;   // 36 x 7
  int py = p / 6, px = p % 6;
  int tid = threadIdx.x, wid = tid >> 6, lane = tid & 63;
  int ntap = (ks < 4) ? 12 : 11;
  int nch = ntap * 4;

  // staging source pointers: call c covers rows [wid*32 + c*8, +8); lane: row=+lane>>3, gran=lane&7
  // LDS dest is linear; source pre-swizzled: gran' = gran ^ (row&7)
  const u16* srcA[4];
  const u16* srcB[4];
#pragma unroll
  for (int c = 0; c < 4; ++c) {
    int row = wid * 32 + c * 8 + (lane >> 3);
    int gsw = ((lane & 7) ^ (row & 7)) * 8;
    srcA[c] = hT + (size_t)row * 102400 + gsw;   // + pix*256 + icc*64
    srcB[c] = w2bT + (size_t)row * 256 + gsw;    // + tap*65536 + icc*64
  }

  f32x4 acc[8][4];
#pragma unroll
  for (int i = 0; i < 8; ++i)
#pragma unroll
    for (int j = 0; j < 4; ++j) acc[i][j] = (f32x4){0.f, 0.f, 0.f, 0.f};

  int wr = wid >> 2, wc = wid & 3;
  int l15 = lane & 15, lh = lane >> 4;

  // prologue: stage chunk 0 into buf 0
  {
    int tap = ks;                       // j=0
    int pix = (2 * py + tap / 9) * 20 + (2 * px + tap % 9);
    int tofsA = pix * 256;
    size_t tofsB = (size_t)tap * 65536;
#pragma unroll
    for (int c = 0; c < 4; ++c) {
      gl_lds16(srcA[c] + tofsA, &Ab[0][(wid * 32 + c * 8) * 64]);
      gl_lds16(srcB[c] + tofsB, &Bb[0][(wid * 32 + c * 8) * 64]);
    }
  }

  for (int ch = 0; ch < nch; ++ch) {
    __syncthreads(); // drains vmcnt -> current buf staged; prev compute done
    int buf = ch & 1;
    if (ch + 1 < nch) {
      int nc2 = ch + 1;
      int tap = (nc2 >> 2) * 7 + ks;
      int icc = nc2 & 3;
      int pix = (2 * py + tap / 9) * 20 + (2 * px + tap % 9);
      int tofsA = pix * 256 + icc * 64;
      size_t tofsB = (size_t)tap * 65536 + icc * 64;
#pragma unroll
      for (int c = 0; c < 4; ++c) {
        gl_lds16(srcA[c] + tofsA, &Ab[buf ^ 1][(wid * 32 + c * 8) * 64]);
        gl_lds16(srcB[c] + tofsB, &Bb[buf ^ 1][(wid * 32 + c * 8) * 64]);
      }
    }
#pragma unroll
    for (int kk = 0; kk < 2; ++kk) {
      int g = kk * 4 + lh;
      short8 br[4];
#pragma unroll
      for (int ni = 0; ni < 4; ++ni) {
        int row = wc * 64 + ni * 16 + l15;
        br[ni] = *(const short8*)&Bb[buf][row * 64 + ((g ^ (row & 7)) * 8)];
      }
#pragma unroll
      for (int mi = 0; mi < 8; ++mi) {
        int row = wr * 128 + mi * 16 + l15;
        short8 ar = *(const short8*)&Ab[buf][row * 64 + ((g ^ (row & 7)) * 8)];
#pragma unroll
        for (int ni = 0; ni < 4; ++ni)
          acc[mi][ni] = __builtin_amdgcn_mfma_f32_16x16x32_bf16(ar, br[ni], acc[mi][ni], 0, 0, 0);
      }
    }
  }

  // epilogue: pp[ks][oc][p][b], float4 over b (4 regs = 4 consecutive b)
  float* ppk = pp + (size_t)ks * 2359296 + (size_t)p * 256;
#pragma unroll
  for (int mi = 0; mi < 8; ++mi) {
    int b = wr * 128 + mi * 16 + lh * 4;
#pragma unroll
    for (int ni = 0; ni < 4; ++ni) {
      int oc = wc * 64 + ni * 16 + l15;
      *(float4*)&ppk[(size_t)oc * 9216 + b] = *(float4*)&acc[mi][ni];
    }
  }
}

// ---------------- split-K reduce + bias: prim2T[flat][b] = sum_ks pp + b2[flat/36] ----------------
__global__ __launch_bounds__(256) void prim_reduce_kernel(
    const float* __restrict__ pp, const float* __restrict__ b2,
    float* __restrict__ prim2T) {
  int e = blockIdx.x * 256 + threadIdx.x;   // float4 index, 589824 total
  int flat = e >> 6;
  float bias = b2[flat / 36];
  const float4* p0 = (const float4*)pp;
  float4 r = p0[e];
#pragma unroll
  for (int ks = 1; ks < 7; ++ks) {
    float4 a = p0[(size_t)ks * 589824 + e];
    r.x += a.x; r.y += a.y; r.z += a.z; r.w += a.w;
  }
  r.x += bias; r.y += bias; r.z += bias; r.w += bias;
  ((float4*)prim2T)[e] = r;
}

// ---------------- softmax over n per class + cb[i][k] = sum_n c*Wb ----------------
__global__ __launch_bounds__(256) void softmax_cb_kernel(
    const float* __restrict__ bij, const float* __restrict__ Wb,
    float* __restrict__ c, float* __restrict__ cb) {
  __shared__ float red[256];
  __shared__ float red2[256][17];
  int i = blockIdx.x, tid = threadIdx.x;
  float m = -1e30f;
  for (int n = tid; n < 1152; n += 256) m = fmaxf(m, bij[i * 1152 + n]);
  red[tid] = m; __syncthreads();
  for (int s = 128; s > 0; s >>= 1) { if (tid < s) red[tid] = fmaxf(red[tid], red[tid + s]); __syncthreads(); }
  m = red[0]; __syncthreads();
  float sum = 0.f;
  for (int n = tid; n < 1152; n += 256) sum += expf(bij[i * 1152 + n] - m);
  red[tid] = sum; __syncthreads();
  for (int s = 128; s > 0; s >>= 1) { if (tid < s) red[tid] += red[tid + s]; __syncthreads(); }
  float inv = 1.0f / red[0];
  float acc[16];
#pragma unroll
  for (int k = 0; k < 16; ++k) acc[k] = 0.f;
  for (int n = tid; n < 1152; n += 256) {
    float cv = expf(bij[i * 1152 + n] - m) * inv;
    c[i * 1152 + n] = cv;
    int mm = i * 1152 + n;
    const float* wb = Wb + (size_t)(mm % 10) * 18432 + (size_t)(mm / 10) * 16;
#pragma unroll
    for (int k = 0; k < 16; ++k) acc[k] += cv * wb[k];
  }
#pragma unroll
  for (int k = 0; k < 16; ++k) red2[tid][k] = acc[k];
  __syncthreads();
  for (int s = 128; s > 0; s >>= 1) {
    if (tid < s) {
#pragma unroll
      for (int k = 0; k < 16; ++k) red2[tid][k] += red2[tid + s][k];
    }
    __syncthreads();
  }
  if (tid < 16) cb[i * 16 + tid] = red2[0][tid];
}

// ---------------- CW[flat][slot][k] = sum_io c[i_lo+slot, n]*W[io,loc,k,c] ----------------
__global__ __launch_bounds__(256) void cw_build_kernel(
    const float* __restrict__ c, const float* __restrict__ W,
    float* __restrict__ CW) {
  int blk = blockIdx.x, tid = threadIdx.x;
  int loc_l = tid >> 5, slot = (tid >> 4) & 1, k = tid & 15;
  int loc = blk * 8 + loc_l;
  int i_lo = (loc * 10) / 1152;
  int i_cls = i_lo + slot;
  float acc[8];
#pragma unroll
  for (int cc = 0; cc < 8; ++cc) acc[cc] = 0.f;
  if (i_cls < 10) {
    for (int io = 0; io < 10; ++io) {
      int mm = loc * 10 + io;
      if (mm / 1152 == i_cls) {
        float cv = c[i_cls * 1152 + mm % 1152];
        const float* wrow = W + (size_t)io * 147456 + (size_t)loc * 128 + k * 8;
        float4 w0 = *(const float4*)wrow;
        float4 w1 = *(const float4*)(wrow + 4);
        acc[0] += cv * w0.x; acc[1] += cv * w0.y; acc[2] += cv * w0.z; acc[3] += cv * w0.w;
        acc[4] += cv * w1.x; acc[5] += cv * w1.y; acc[6] += cv * w1.z; acc[7] += cv * w1.w;
      }
    }
  }
#pragma unroll
  for (int cc = 0; cc < 8; ++cc)
    CW[(size_t)(loc * 8 + cc) * 32 + slot * 16 + k] = acc[cc];
}

// ---------------- vgemm: vp[ch][i][b][k] = sum_{loc in chunk} prim2T*CW ----------------
__global__ __launch_bounds__(256) void vgemm_kernel(
    const float* __restrict__ prim2T, const float* __restrict__ CW,
    float* __restrict__ vp) {
  __shared__ float cws[1920]; // [15 loc][8 c][16 k]
  int ch = blockIdx.x, i = blockIdx.y, tid = threadIdx.x;
  int loc_min = (i * 1152) / 10;
  int loc_max = ((i + 1) * 1152 - 1) / 10;
  int lc0 = loc_min + ch * 15;
  for (int t = tid; t < 1920; t += 256) {
    int ll = t >> 7, rem = t & 127;
    int loc = lc0 + ll;
    float v = 0.f;
    if (loc <= loc_max) {
      int slot = i - (loc * 10) / 1152;
      int cc = rem >> 4, k = rem & 15;
      v = CW[(size_t)(loc * 8 + cc) * 32 + slot * 16 + k];
    }
    cws[t] = v;
  }
  __syncthreads();
  float acc[16];
#pragma unroll
  for (int k = 0; k < 16; ++k) acc[k] = 0.f;
  for (int ll = 0; ll < 15; ++ll) {
    int loc = lc0 + ll;
    if (loc > loc_max) break;
    const float* pr = prim2T + (size_t)loc * 8 * 256 + tid;
    const float* cw = cws + ll * 128;
#pragma unroll
    for (int cc = 0; cc < 8; ++cc) {
      float pvv = pr[cc * 256];
      float4 a0 = *(const float4*)&cw[cc * 16];
      float4 a1 = *(const float4*)&cw[cc * 16 + 4];
      float4 a2 = *(const float4*)&cw[cc * 16 + 8];
      float4 a3 = *(const float4*)&cw[cc * 16 + 12];
      acc[0] += pvv * a0.x; acc[1] += pvv * a0.y; acc[2] += pvv * a0.z; acc[3] += pvv * a0.w;
      acc[4] += pvv * a1.x; acc[5] += pvv * a1.y; acc[6] += pvv * a1.z; acc[7] += pvv * a1.w;
      acc[8] += pvv * a2.x; acc[9] += pvv * a2.y; acc[10] += pvv * a2.z; acc[11] += pvv * a2.w;
      acc[12] += pvv * a3.x; acc[13] += pvv * a3.y; acc[14] += pvv * a3.z; acc[15] += pvv * a3.w;
    }
  }
  float* dst = vp + ((size_t)(ch * 10 + i) * 256 + tid) * 16;
#pragma unroll
  for (int k = 0; k < 16; ++k) dst[k] = acc[k];
}

// ---------------- squash_combine: v = squash(sum_ch vp + cb); sv; out on final ----------------
__global__ __launch_bounds__(256) void squash_combine_kernel(
    const float* __restrict__ vp, const float* __restrict__ cb,
    float* __restrict__ v2, float* __restrict__ sv, float* __restrict__ out, int finalf) {
  __shared__ float red[256];
  __shared__ float red2[256][17];
  int i = blockIdx.x, tid = threadIdx.x;
  float vpre[16];
#pragma unroll
  for (int k = 0; k < 16; ++k) vpre[k] = cb[i * 16 + k];
  for (int ch = 0; ch < 8; ++ch) {
    const float4* src = (const float4*)(vp + ((size_t)(ch * 10 + i) * 256 + tid) * 16);
#pragma unroll
    for (int q = 0; q < 4; ++q) {
      float4 a = src[q];
      vpre[q * 4 + 0] += a.x; vpre[q * 4 + 1] += a.y; vpre[q * 4 + 2] += a.z; vpre[q * 4 + 3] += a.w;
    }
  }
  float ss = 0.f;
#pragma unroll
  for (int k = 0; k < 16; ++k) { ss += vpre[k] * vpre[k]; red2[tid][k] = vpre[k]; }
  red[tid] = ss; __syncthreads();
  for (int s = 128; s > 0; s >>= 1) {
    if (tid < s) {
      red[tid] += red[tid + s];
#pragma unroll
      for (int k = 0; k < 16; ++k) red2[tid][k] += red2[tid + s][k];
    }
    __syncthreads();
  }
  float nrm = sqrtf(red[0]);
  float n2 = nrm * nrm;
  float scale = nrm / (1.f + n2);
  if (tid < 16) sv[i * 16 + tid] = scale * red2[0][tid];
  float* dst = (finalf ? out : v2) + (size_t)i * 4096 + tid * 16;
#pragma unroll
  for (int k = 0; k < 16; ++k) dst[k] = vpre[k] * scale;
}

// ---------------- pv: P[flat][slot][k] = sum_b prim2T[flat][b]*v2[cls][b][k] ----------------
__global__ __launch_bounds__(256) void pv_kernel(
    const float* __restrict__ prim2T, const float* __restrict__ v2,
    float* __restrict__ P) {
  __shared__ float ps[64 * 260];      // [flat_l][b] padded
  __shared__ float vs[2 * 16 * 260];  // [cl][k][b] padded
  int blk = blockIdx.x, tid = threadIdx.x;
  int loc0 = blk * 8;
  int I = (loc0 * 10) / 1152;
  for (int t = tid; t < 4096; t += 256) {
    int row = t >> 6, seg = t & 63;
    float4 a = *(const float4*)(prim2T + (size_t)(loc0 * 8 + row) * 256 + seg * 4);
    *(float4*)&ps[row * 260 + seg * 4] = a;
  }
  for (int cl = 0; cl < 2; ++cl) {
    int cls = I + cl;
    for (int t = tid; t < 4096; t += 256) {
      int b = t >> 4, k = t & 15;
      float val = (cls <= 9) ? v2[(size_t)cls * 4096 + t] : 0.f;
      vs[(cl * 16 + k) * 260 + b] = val;
    }
  }
  __syncthreads();
  int k = tid & 15, fs = tid >> 4;
  const float4* ps4 = (const float4*)ps;
  const float4* vs4 = (const float4*)vs;
#pragma unroll
  for (int q = 0; q < 8; ++q) {
    int flat_l = fs * 4 + (q & 3);
    int slot = q >> 2;
    int loc = loc0 + (flat_l >> 3);
    int cls = (loc * 10) / 1152 + slot;
    int cl_idx = cls - I;
    if (cl_idx <= 1 && cls <= 9) {
      float a = 0.f;
      int bp = flat_l * 65, bv = (cl_idx * 16 + k) * 65;
      for (int b4 = 0; b4 < 64; ++b4) {
        float4 p4 = ps4[bp + b4];
        float4 w4 = vs4[bv + b4];
        a += p4.x * w4.x + p4.y * w4.y + p4.z * w4.z + p4.w * w4.w;
      }
      P[(size_t)(loc0 * 8 + flat_l) * 32 + slot * 16 + k] = a;
    }
  }
}

// ---------------- bij_assemble: bij[m] += sum_{c,k} W*P + Wb.sv ----------------
__global__ __launch_bounds__(256) void bij_assemble_kernel(
    const float* __restrict__ W, const float* __restrict__ Wb,
    const float* __restrict__ P, const float* __restrict__ sv,
    float* __restrict__ bij) {
  int m = blockIdx.x * 256 + threadIdx.x;
  int i = m / 1152, loc = m / 10, io = m % 10;
  int slot = i - (loc * 10) / 1152;
  const float* wrow = W + (size_t)io * 147456 + (size_t)loc * 128;
  const float* prow = P + (size_t)(loc * 8) * 32 + slot * 16;
  float s = 0.f;
#pragma unroll
  for (int k = 0; k < 16; ++k) {
    float4 w0 = *(const float4*)(wrow + k * 8);
    float4 w1 = *(const float4*)(wrow + k * 8 + 4);
    s += w0.x * prow[0 * 32 + k] + w0.y * prow[1 * 32 + k] + w0.z * prow[2 * 32 + k] + w0.w * prow[3 * 32 + k];
    s += w1.x * prow[4 * 32 + k] + w1.y * prow[5 * 32 + k] + w1.z * prow[6 * 32 + k] + w1.w * prow[7 * 32 + k];
  }
  const float* wbr = Wb + (size_t)io * 18432 + (size_t)loc * 16;
  const float* svr = sv + i * 16;
#pragma unroll
  for (int k = 0; k < 16; ++k) s += wbr[k] * svr[k];
  bij[m] += s;
}

extern "C" void kernel_launch(void* const* d_in, const int* in_sizes, int n_in,
                              void* d_out, int out_size, void* d_ws, size_t ws_size,
                              hipStream_t stream) {
  const float* x  = (const float*)d_in[0];
  const float* w1 = (const float*)d_in[1];
  const float* b1 = (const float*)d_in[2];
  const float* w2 = (const float*)d_in[3];
  const float* b2 = (const float*)d_in[4];
  const float* W  = (const float*)d_in[5];
  const float* Wb = (const float*)d_in[6];
  float* out = (float*)d_out;

  // workspace layout (~142 MB)
  u16*   hT     = (u16*)d_ws;                    // 26,214,400 u16
  u16*   w2bT   = hT + 26214400;                 //  5,308,416 u16
  float* pp     = (float*)(w2bT + 5308416);      //  7*2,359,296 f
  float* prim2T = pp + 7 * 2359296;              //  2,359,296 f
  float* CW     = prim2T + 2359296;              //    294,912 f
  float* P      = CW + 294912;                   //    294,912 f
  float* vp     = P + 294912;                    //    327,680 f
  float* v2     = vp + 327680;                   //     40,960 f
  float* cbuf   = v2 + 40960;                    //     11,520 f
  float* bij    = cbuf + 11520;                  //     11,520 f
  float* cb     = bij + 11520;                   //        160 f
  float* sv     = cb + 160;                      //        160 f

  hipMemsetAsync(bij, 0, 11520 * sizeof(float), stream);

  conv1_kernel<<<dim3(256, 2), 256, 0, stream>>>(x, w1, b1, hT);
  w2b_kernel<<<256, 256, 0, stream>>>(w2, w2bT);
  conv2_mfma_kernel<<<dim3(36, 7), 512, 0, stream>>>(hT, w2bT, pp);
  prim_reduce_kernel<<<2304, 256, 0, stream>>>(pp, b2, prim2T);

  for (int r = 0; r < 3; ++r) {
    softmax_cb_kernel<<<10, 256, 0, stream>>>(bij, Wb, cbuf, cb);
    cw_build_kernel<<<144, 256, 0, stream>>>(cbuf, W, CW);
    vgemm_kernel<<<dim3(8, 10), 256, 0, stream>>>(prim2T, CW, vp);
    squash_combine_kernel<<<10, 256, 0, stream>>>(vp, cb, v2, sv, out, r == 2 ? 1 : 0);
    if (r < 2) {
      pv_kernel<<<144, 256, 0, stream>>>(prim2T, v2, P);
      bij_assemble_kernel<<<45, 256, 0, stream>>>(W, Wb, P, sv, bij);
    }
  }
}